// Round 4
// baseline (3094.086 us; speedup 1.0000x reference)
//
#include <hip/hip_runtime.h>

#define NM 1200
#define PP 719400      // NM*(NM-1)/2
#define HID 128
#define RANK 64
#define SDP_ITERS 100

// ---------------- ws layout (floats) ----------------
#define OFF_S      0
#define OFF_SUMW2  1600
#define OFF_CVEC   1664
#define OFF_W1S    1792
#define OFF_WVEC   6912
#define OFF_WMAT   726400
#define OFF_VA     2166400
#define OFF_VB     2243200

__device__ __forceinline__ float wave_reduce_sum(float v) {
#pragma unroll
    for (int o = 32; o > 0; o >>= 1) v += __shfl_xor(v, o, 64);
    return v;
}

__global__ __launch_bounds__(256) void zero_kernel(float* __restrict__ ws, int n) {
    int i = blockIdx.x * 256 + threadIdx.x;
    if (i < n) ws[i] = 0.0f;
}

// ---- pass 1: S[40x40] = [x | 1]^T [x | 1]; 8x8 frags, ds_read_b128 ----
#define STATS_BLOCKS 1024
__global__ __launch_bounds__(256) void stats_kernel(const float* __restrict__ x,
                                                    float* __restrict__ S) {
    __shared__ __align__(16) float tile[40 * 40];
    __shared__ float Sacc[1600];
    const int tid = threadIdx.x;
    for (int i = tid; i < 1600; i += 256) Sacc[i] = 0.f;

    const int rpb = (PP + STATS_BLOCKS - 1) / STATS_BLOCKS;  // 703
    const int r0 = blockIdx.x * rpb;
    const int r1 = min(r0 + rpb, PP);

    const int z = tid / 25;          // 0..9 (tid<250)
    const int q = tid - z * 25;
    const int ty = q / 5, tx = q - ty * 5;
    const bool active = (tid < 250);

    float acc[8][8];
#pragma unroll
    for (int a = 0; a < 8; ++a)
#pragma unroll
        for (int b = 0; b < 8; ++b) acc[a][b] = 0.f;

    for (int t = r0; t < r1; t += 40) {
        const int nr = min(40, r1 - t);
        __syncthreads();
        const float* xg = x + (size_t)t * 39;
        for (int idx = tid; idx < 1560; idx += 256) {
            int rr = idx / 39, cc = idx - rr * 39;
            tile[rr * 40 + cc] = (rr < nr) ? xg[idx] : 0.f;
        }
        for (int rr = tid; rr < 40; rr += 256)
            tile[rr * 40 + 39] = (rr < nr) ? 1.0f : 0.f;
        __syncthreads();
        if (active) {
#pragma unroll
            for (int s = 0; s < 4; ++s) {
                const float* row = &tile[(z + s * 10) * 40];
                float4 a0 = *(const float4*)(row + ty * 8);
                float4 a1 = *(const float4*)(row + ty * 8 + 4);
                float4 b0 = *(const float4*)(row + tx * 8);
                float4 b1 = *(const float4*)(row + tx * 8 + 4);
                float av[8] = {a0.x, a0.y, a0.z, a0.w, a1.x, a1.y, a1.z, a1.w};
                float bv[8] = {b0.x, b0.y, b0.z, b0.w, b1.x, b1.y, b1.z, b1.w};
#pragma unroll
                for (int a = 0; a < 8; ++a)
#pragma unroll
                    for (int b = 0; b < 8; ++b)
                        acc[a][b] = fmaf(av[a], bv[b], acc[a][b]);
            }
        }
    }
    __syncthreads();
    if (active) {
#pragma unroll
        for (int a = 0; a < 8; ++a)
#pragma unroll
            for (int b = 0; b < 8; ++b)
                atomicAdd(&Sacc[(ty * 8 + a) * 40 + tx * 8 + b], acc[a][b]);
    }
    __syncthreads();
    for (int i = tid; i < 1600; i += 256) atomicAdd(&S[i], Sacc[i]);
}

// ---- BN folding ----
__global__ __launch_bounds__(64) void bn_prep(const float* __restrict__ S,
                                              const float* __restrict__ W1,
                                              const float* __restrict__ gamma,
                                              const float* __restrict__ beta,
                                              float* __restrict__ W1s,
                                              float* __restrict__ cvec) {
    const int j = blockIdx.x;
    const int l = threadIdx.x;
    const float invP = 1.0f / (float)PP;
    float q = 0.f;
    for (int idx = l; idx < 39 * 39; idx += 64) {
        int a = idx / 39, b = idx - a * 39;
        q = fmaf(S[a * 40 + b], W1[a * HID + j] * W1[b * HID + j], q);
    }
    float s1 = (l < 39) ? (S[39 * 40 + l] * invP) * W1[l * HID + j] : 0.f;
    q = wave_reduce_sum(q);
    s1 = wave_reduce_sum(s1);
    float var = q * invP - s1 * s1;
    float scale = gamma[j] * (1.0f / sqrtf(var + 1e-5f));
    for (int a = l; a < 39; a += 64) W1s[a * HID + j] = W1[a * HID + j] * scale;
    if (l == 0) cvec[j] = -s1 * scale + beta[j];
}

// ---- fused MLP: explicit 2x64 strip-mine ----
__global__ __launch_bounds__(256) void mlp_kernel(const float* __restrict__ x,
                                                  const float* __restrict__ W1s,
                                                  const float* __restrict__ cvec,
                                                  const float* __restrict__ W2,
                                                  const float* __restrict__ b2,
                                                  float* __restrict__ w,
                                                  float* __restrict__ sumw2) {
    __shared__ float xt[256 * 39];
    __shared__ float red[4];
    const size_t base = (size_t)blockIdx.x * 256;
    {
        const size_t g0 = base * 39;
        const size_t gmax = (size_t)PP * 39;
        for (int idx = threadIdx.x; idx < 256 * 39; idx += 256) {
            size_t g = g0 + idx;
            xt[idx] = (g < gmax) ? x[g] : 0.f;
        }
    }
    __syncthreads();

    const float* xrow = &xt[threadIdx.x * 39];
    float wacc = 0.f;
#pragma unroll 1
    for (int c = 0; c < 2; ++c) {
        float acc[64];
#pragma unroll
        for (int jj = 0; jj < 64; ++jj) acc[jj] = cvec[c * 64 + jj];
        for (int k = 0; k < 39; ++k) {
            const float xk = xrow[k];
            const float* wrow = &W1s[k * HID + c * 64];
#pragma unroll
            for (int jj = 0; jj < 64; ++jj) acc[jj] = fmaf(xk, wrow[jj], acc[jj]);
        }
#pragma unroll
        for (int jj = 0; jj < 64; ++jj)
            wacc = fmaf(fmaxf(acc[jj], 0.f), W2[c * 64 + jj], wacc);
    }

    const size_t p = base + threadIdx.x;
    const float wv = wacc + b2[0];
    float sq = 0.f;
    if (p < (size_t)PP) { w[p] = wv; sq = wv * wv; }
    sq = wave_reduce_sum(sq);
    if ((threadIdx.x & 63) == 0) red[threadIdx.x >> 6] = sq;
    __syncthreads();
    if (threadIdx.x == 0) atomicAdd(sumw2, red[0] + red[1] + red[2] + red[3]);
}

// ---- W build ----
__global__ __launch_bounds__(256) void buildW(const float* __restrict__ w,
                                              float* __restrict__ W) {
    __shared__ float tile[16][17];
    const int bi = blockIdx.y, bj = blockIdx.x;
    if (bi > bj) return;
    const int ty = threadIdx.x >> 4, tx = threadIdx.x & 15;
    const int i = bi * 16 + ty, j = bj * 16 + tx;
    float v = 0.f;
    if (i < j) {
        int p = i * (NM - 1) - (i * (i - 1)) / 2 + (j - i - 1);
        v = w[p];
    }
    tile[ty][tx] = v;
    __syncthreads();
    if (bi == bj) {
        float out = (i < j) ? v : ((i > j) ? tile[tx][ty] : 0.f);
        W[(size_t)i * NM + j] = out;
    } else {
        W[(size_t)i * NM + j] = v;
        W[(size_t)(bj * 16 + ty) * NM + (bi * 16 + tx)] = tile[tx][ty];
    }
}

// ---- V = V0 / ||row|| ----
__global__ __launch_bounds__(256) void v0norm(const float* __restrict__ V0,
                                              float* __restrict__ V) {
    const int i = blockIdx.x * 4 + (threadIdx.x >> 6);
    const int c = threadIdx.x & 63;
    float v = V0[(size_t)i * RANK + c];
    float s = wave_reduce_sum(v * v);
    V[(size_t)i * RANK + c] = v * (1.0f / sqrtf(s));
}

// ---- one SDP step: Vout = rownorm(Vin + lr * W @ Vin) ----
// 300 blocks x 256: block owns 4 rows; wave = K-quarter (300); lane = (r, g).
// W read direct from L2 (broadcast dwords), V coalesced float4; LDS only 4 KB.
__global__ __launch_bounds__(256) void sdp_step(const float* __restrict__ Vin,
                                                float* __restrict__ Vout,
                                                const float* __restrict__ W,
                                                const float* __restrict__ sumw2) {
    __shared__ __align__(16) float part[4][4][64];   // [kq][r][c], 4 KB
    const int tid = threadIdx.x;
    const int kq = tid >> 6;
    const int lane = tid & 63;
    const int r = lane >> 4;
    const int g = lane & 15;
    const int i0 = blockIdx.x * 4;

    const float* __restrict__ Wr = W + (size_t)(i0 + r) * NM + kq * 300;
    const float4* __restrict__ Vp = (const float4*)Vin + (size_t)(kq * 300) * 16 + g;

    float4 acc = {0.f, 0.f, 0.f, 0.f};
#pragma unroll 6
    for (int t = 0; t < 300; ++t) {
        const float wv = Wr[t];
        const float4 v = Vp[t * 16];
        acc.x = fmaf(wv, v.x, acc.x);
        acc.y = fmaf(wv, v.y, acc.y);
        acc.z = fmaf(wv, v.z, acc.z);
        acc.w = fmaf(wv, v.w, acc.w);
    }
    *(float4*)&part[kq][r][g * 4] = acc;
    __syncthreads();

    const int r2 = tid >> 6, c2 = tid & 63;
    float s = part[0][r2][c2] + part[1][r2][c2] + part[2][r2][c2] + part[3][r2][c2];
    const float lr = 1.0f / (sqrtf(2.0f * sumw2[0]) + 1e-8f);
    float y = Vin[(size_t)(i0 + r2) * RANK + c2] + lr * s;
    float n = wave_reduce_sum(y * y);
    Vout[(size_t)(i0 + r2) * RANK + c2] = y * (1.0f / sqrtf(n));
}

// ---- out = clip(V V^T, 0, 1): 128x128 symmetric tiles, 8x8 frags ----
__global__ __launch_bounds__(256) void vvt_kernel(const float* __restrict__ V,
                                                  float* __restrict__ out) {
    const int bi = blockIdx.y, bj = blockIdx.x;
    if (bi > bj) return;
    __shared__ __align__(16) float Ti[64][132];   // [k][row]
    __shared__ __align__(16) float Tj[64][132];
    const int tid = threadIdx.x;
    for (int idx = tid; idx < 128 * 64; idx += 256) {
        int row = idx >> 6, k = idx & 63;
        int gi = bi * 128 + row, gj = bj * 128 + row;
        Ti[k][row] = (gi < NM) ? V[(size_t)gi * RANK + k] : 0.f;
        Tj[k][row] = (gj < NM) ? V[(size_t)gj * RANK + k] : 0.f;
    }
    __syncthreads();
    const int ty = tid >> 4, tx = tid & 15;
    float acc[8][8];
#pragma unroll
    for (int a = 0; a < 8; ++a)
#pragma unroll
        for (int b = 0; b < 8; ++b) acc[a][b] = 0.f;
    for (int k = 0; k < 64; ++k) {
        float4 a0 = *(const float4*)&Ti[k][ty * 8];
        float4 a1 = *(const float4*)&Ti[k][ty * 8 + 4];
        float4 b0 = *(const float4*)&Tj[k][tx * 8];
        float4 b1 = *(const float4*)&Tj[k][tx * 8 + 4];
        float av[8] = {a0.x, a0.y, a0.z, a0.w, a1.x, a1.y, a1.z, a1.w};
        float bv[8] = {b0.x, b0.y, b0.z, b0.w, b1.x, b1.y, b1.z, b1.w};
#pragma unroll
        for (int a = 0; a < 8; ++a)
#pragma unroll
            for (int b = 0; b < 8; ++b)
                acc[a][b] = fmaf(av[a], bv[b], acc[a][b]);
    }
    // normal stores: rows i = bi*128+8ty+a, cols j = bj*128+8tx (+8)
#pragma unroll
    for (int a = 0; a < 8; ++a) {
        int i = bi * 128 + 8 * ty + a;
        if (i >= NM) break;
        int jb = bj * 128 + 8 * tx;
        if (jb + 7 < NM) {
            float4 s0 = {fminf(fmaxf(acc[a][0], 0.f), 1.f), fminf(fmaxf(acc[a][1], 0.f), 1.f),
                         fminf(fmaxf(acc[a][2], 0.f), 1.f), fminf(fmaxf(acc[a][3], 0.f), 1.f)};
            float4 s1 = {fminf(fmaxf(acc[a][4], 0.f), 1.f), fminf(fmaxf(acc[a][5], 0.f), 1.f),
                         fminf(fmaxf(acc[a][6], 0.f), 1.f), fminf(fmaxf(acc[a][7], 0.f), 1.f)};
            *(float4*)&out[(size_t)i * NM + jb] = s0;
            *(float4*)&out[(size_t)i * NM + jb + 4] = s1;
        } else {
#pragma unroll
            for (int b = 0; b < 8; ++b) {
                int j = jb + b;
                if (j < NM) out[(size_t)i * NM + j] = fminf(fmaxf(acc[a][b], 0.f), 1.f);
            }
        }
    }
    if (bi != bj) {
        // mirrored: row j = bj*128+8tx+b, cols i = bi*128+8ty (+8)
#pragma unroll
        for (int b = 0; b < 8; ++b) {
            int j = bj * 128 + 8 * tx + b;
            if (j >= NM) break;
            int ib = bi * 128 + 8 * ty;
            if (ib + 7 < NM) {
                float4 s0 = {fminf(fmaxf(acc[0][b], 0.f), 1.f), fminf(fmaxf(acc[1][b], 0.f), 1.f),
                             fminf(fmaxf(acc[2][b], 0.f), 1.f), fminf(fmaxf(acc[3][b], 0.f), 1.f)};
                float4 s1 = {fminf(fmaxf(acc[4][b], 0.f), 1.f), fminf(fmaxf(acc[5][b], 0.f), 1.f),
                             fminf(fmaxf(acc[6][b], 0.f), 1.f), fminf(fmaxf(acc[7][b], 0.f), 1.f)};
                *(float4*)&out[(size_t)j * NM + ib] = s0;
                *(float4*)&out[(size_t)j * NM + ib + 4] = s1;
            } else {
#pragma unroll
                for (int a = 0; a < 8; ++a) {
                    int i = ib + a;
                    if (i < NM) out[(size_t)j * NM + i] = fminf(fmaxf(acc[a][b], 0.f), 1.f);
                }
            }
        }
    }
}

extern "C" void kernel_launch(void* const* d_in, const int* in_sizes, int n_in,
                              void* d_out, int out_size, void* d_ws, size_t ws_size,
                              hipStream_t stream) {
    const float* x     = (const float*)d_in[0];
    const float* W1    = (const float*)d_in[1];
    const float* gamma = (const float*)d_in[3];
    const float* beta  = (const float*)d_in[4];
    const float* W2    = (const float*)d_in[5];
    const float* b2    = (const float*)d_in[6];
    const float* V0    = (const float*)d_in[7];
    float* out = (float*)d_out;

    float* ws    = (float*)d_ws;
    float* S     = ws + OFF_S;
    float* sumw2 = ws + OFF_SUMW2;
    float* cvec  = ws + OFF_CVEC;
    float* W1s   = ws + OFF_W1S;
    float* wvec  = ws + OFF_WVEC;
    float* Wmat  = ws + OFF_WMAT;
    float* Va    = ws + OFF_VA;
    float* Vb    = ws + OFF_VB;

    zero_kernel<<<7, 256, 0, stream>>>(ws, OFF_W1S);   // S + sumw2
    stats_kernel<<<STATS_BLOCKS, 256, 0, stream>>>(x, S);
    bn_prep<<<HID, 64, 0, stream>>>(S, W1, gamma, beta, W1s, cvec);
    mlp_kernel<<<(PP + 255) / 256, 256, 0, stream>>>(x, W1s, cvec, W2, b2, wvec, sumw2);
    buildW<<<dim3(75, 75), 256, 0, stream>>>(wvec, Wmat);
    v0norm<<<NM / 4, 256, 0, stream>>>(V0, Va);
    for (int it = 0; it < SDP_ITERS; ++it) {
        const float* vin = (it & 1) ? Vb : Va;
        float* vout      = (it & 1) ? Va : Vb;
        sdp_step<<<NM / 4, 256, 0, stream>>>(vin, vout, Wmat, sumw2);
    }
    // iter 99 (odd) writes Va
    vvt_kernel<<<dim3(10, 10), 256, 0, stream>>>(Va, out);
}

// Round 5
// 1339.648 us; speedup vs baseline: 2.3096x; 2.3096x over previous
//
#include <hip/hip_runtime.h>

#define NM 1200
#define PP 719400      // NM*(NM-1)/2
#define HID 128
#define RANK 64
#define SDP_ITERS 100

// ---------------- ws layout (floats) ----------------
#define OFF_S      0
#define OFF_SUMW2  1600
#define OFF_CVEC   1664
#define OFF_W1S    1792
#define OFF_WVEC   6912
#define OFF_WMAT   726400
#define OFF_VA     2166400
#define OFF_VB     2243200

__device__ __forceinline__ float wave_reduce_sum(float v) {
#pragma unroll
    for (int o = 32; o > 0; o >>= 1) v += __shfl_xor(v, o, 64);
    return v;
}

__global__ __launch_bounds__(256) void zero_kernel(float* __restrict__ ws, int n) {
    int i = blockIdx.x * 256 + threadIdx.x;
    if (i < n) ws[i] = 0.0f;
}

// ---- pass 1: S[40x40] = [x | 1]^T [x | 1] ----
// 48-padded tile, 8x8 lane grid, 6x6 frags via float2 (bank-disjoint broadcast),
// 4-wave z-split over k. All 256 threads active.
#define STATS_BLOCKS 1024
#define KT 40                      // k-rows per tile
__global__ __launch_bounds__(256) void stats_kernel(const float* __restrict__ x,
                                                    float* __restrict__ S) {
    __shared__ __align__(8) float tile[KT * 48];
    __shared__ float Sacc[48 * 48];
    const int tid = threadIdx.x;
    for (int i = tid; i < 48 * 48; i += 256) Sacc[i] = 0.f;

    const int rpb = (PP + STATS_BLOCKS - 1) / STATS_BLOCKS;  // 703
    const int r0 = blockIdx.x * rpb;
    const int r1 = min(r0 + rpb, PP);

    const int z  = tid >> 6;          // wave id 0..3 -> k offset
    const int ln = tid & 63;
    const int ty = ln >> 3, tx = ln & 7;

    float acc[6][6];
#pragma unroll
    for (int a = 0; a < 6; ++a)
#pragma unroll
        for (int b = 0; b < 6; ++b) acc[a][b] = 0.f;

    for (int t = r0; t < r1; t += KT) {
        const int nr = min(KT, r1 - t);
        __syncthreads();
        const float* xg = x + (size_t)t * 39;
        for (int idx = tid; idx < KT * 48; idx += 256) {
            int rr = idx / 48, cc = idx - rr * 48;
            float v = 0.f;
            if (rr < nr) {
                if (cc < 39) v = xg[rr * 39 + cc];
                else if (cc == 39) v = 1.0f;
            }
            tile[idx] = v;
        }
        __syncthreads();
#pragma unroll 2
        for (int kk = 0; kk < KT / 4; ++kk) {
            const float* row = &tile[(kk * 4 + z) * 48];
            float2 a0 = *(const float2*)(row + ty * 6);
            float2 a1 = *(const float2*)(row + ty * 6 + 2);
            float2 a2 = *(const float2*)(row + ty * 6 + 4);
            float2 b0 = *(const float2*)(row + tx * 6);
            float2 b1 = *(const float2*)(row + tx * 6 + 2);
            float2 b2 = *(const float2*)(row + tx * 6 + 4);
            float av[6] = {a0.x, a0.y, a1.x, a1.y, a2.x, a2.y};
            float bv[6] = {b0.x, b0.y, b1.x, b1.y, b2.x, b2.y};
#pragma unroll
            for (int a = 0; a < 6; ++a)
#pragma unroll
                for (int b = 0; b < 6; ++b)
                    acc[a][b] = fmaf(av[a], bv[b], acc[a][b]);
        }
    }
    __syncthreads();
#pragma unroll
    for (int a = 0; a < 6; ++a)
#pragma unroll
        for (int b = 0; b < 6; ++b)
            atomicAdd(&Sacc[(ty * 6 + a) * 48 + tx * 6 + b], acc[a][b]);
    __syncthreads();
    for (int i = tid; i < 1600; i += 256) {
        int r = i / 40, c = i - r * 40;
        atomicAdd(&S[i], Sacc[r * 48 + c]);
    }
}

// ---- BN folding ----
__global__ __launch_bounds__(64) void bn_prep(const float* __restrict__ S,
                                              const float* __restrict__ W1,
                                              const float* __restrict__ gamma,
                                              const float* __restrict__ beta,
                                              float* __restrict__ W1s,
                                              float* __restrict__ cvec) {
    const int j = blockIdx.x;
    const int l = threadIdx.x;
    const float invP = 1.0f / (float)PP;
    float q = 0.f;
    for (int idx = l; idx < 39 * 39; idx += 64) {
        int a = idx / 39, b = idx - a * 39;
        q = fmaf(S[a * 40 + b], W1[a * HID + j] * W1[b * HID + j], q);
    }
    float s1 = (l < 39) ? (S[39 * 40 + l] * invP) * W1[l * HID + j] : 0.f;
    q = wave_reduce_sum(q);
    s1 = wave_reduce_sum(s1);
    float var = q * invP - s1 * s1;
    float scale = gamma[j] * (1.0f / sqrtf(var + 1e-5f));
    for (int a = l; a < 39; a += 64) W1s[a * HID + j] = W1[a * HID + j] * scale;
    if (l == 0) cvec[j] = -s1 * scale + beta[j];
}

// ---- fused MLP: xr[39] in registers, 2x64 strip-mine, inner loop s_load+FMA only ----
__global__ __launch_bounds__(256) void mlp_kernel(const float* __restrict__ x,
                                                  const float* __restrict__ W1s,
                                                  const float* __restrict__ cvec,
                                                  const float* __restrict__ W2,
                                                  const float* __restrict__ b2,
                                                  float* __restrict__ w,
                                                  float* __restrict__ sumw2) {
    __shared__ float xt[256 * 39];
    __shared__ float red[4];
    const size_t base = (size_t)blockIdx.x * 256;
    {
        const size_t g0 = base * 39;
        const size_t gmax = (size_t)PP * 39;
        for (int idx = threadIdx.x; idx < 256 * 39; idx += 256) {
            size_t g = g0 + idx;
            xt[idx] = (g < gmax) ? x[g] : 0.f;
        }
    }
    __syncthreads();

    float xr[39];
    {
        const float* xrow = &xt[threadIdx.x * 39];
#pragma unroll
        for (int k = 0; k < 39; ++k) xr[k] = xrow[k];
    }

    float wacc = 0.f;
#pragma unroll 1
    for (int c = 0; c < 2; ++c) {
        float acc[64];
#pragma unroll
        for (int jj = 0; jj < 64; ++jj) acc[jj] = cvec[c * 64 + jj];
#pragma unroll 3
        for (int k = 0; k < 39; ++k) {
            const float xk = xr[k];
            const float* wrow = &W1s[k * HID + c * 64];
#pragma unroll
            for (int jj = 0; jj < 64; ++jj) acc[jj] = fmaf(xk, wrow[jj], acc[jj]);
        }
#pragma unroll
        for (int jj = 0; jj < 64; ++jj)
            wacc = fmaf(fmaxf(acc[jj], 0.f), W2[c * 64 + jj], wacc);
    }

    const size_t p = base + threadIdx.x;
    const float wv = wacc + b2[0];
    float sq = 0.f;
    if (p < (size_t)PP) { w[p] = wv; sq = wv * wv; }
    sq = wave_reduce_sum(sq);
    if ((threadIdx.x & 63) == 0) red[threadIdx.x >> 6] = sq;
    __syncthreads();
    if (threadIdx.x == 0) atomicAdd(sumw2, red[0] + red[1] + red[2] + red[3]);
}

// ---- W build ----
__global__ __launch_bounds__(256) void buildW(const float* __restrict__ w,
                                              float* __restrict__ W) {
    __shared__ float tile[16][17];
    const int bi = blockIdx.y, bj = blockIdx.x;
    if (bi > bj) return;
    const int ty = threadIdx.x >> 4, tx = threadIdx.x & 15;
    const int i = bi * 16 + ty, j = bj * 16 + tx;
    float v = 0.f;
    if (i < j) {
        int p = i * (NM - 1) - (i * (i - 1)) / 2 + (j - i - 1);
        v = w[p];
    }
    tile[ty][tx] = v;
    __syncthreads();
    if (bi == bj) {
        float out = (i < j) ? v : ((i > j) ? tile[tx][ty] : 0.f);
        W[(size_t)i * NM + j] = out;
    } else {
        W[(size_t)i * NM + j] = v;
        W[(size_t)(bj * 16 + ty) * NM + (bi * 16 + tx)] = tile[tx][ty];
    }
}

// ---- V = V0 / ||row|| ----
__global__ __launch_bounds__(256) void v0norm(const float* __restrict__ V0,
                                              float* __restrict__ V) {
    const int i = blockIdx.x * 4 + (threadIdx.x >> 6);
    const int c = threadIdx.x & 63;
    float v = V0[(size_t)i * RANK + c];
    float s = wave_reduce_sum(v * v);
    V[(size_t)i * RANK + c] = v * (1.0f / sqrtf(s));
}

// ---- one SDP step: Vout = rownorm(Vin + lr * W @ Vin) ----
// 200 blocks x 512 threads (8 waves). Block owns 6 rows; wave = K/8 chunk (150 j);
// lane = column. j wave-uniform -> W via scalar loads (readfirstlane base);
// V load = one fully-coalesced 256B global_load_dword per j.
__global__ __launch_bounds__(512) void sdp_step(const float* __restrict__ Vin,
                                                float* __restrict__ Vout,
                                                const float* __restrict__ W,
                                                const float* __restrict__ sumw2) {
    __shared__ float part[8][6][64];   // 12 KB
    const int tid = threadIdx.x;
    const int c = tid & 63;
    const int wvid = tid >> 6;                      // 0..7
    const int i0 = blockIdx.x * 6;
    const int j0 = __builtin_amdgcn_readfirstlane(wvid * 150);

    const float* __restrict__ Wb = W + (size_t)i0 * NM + j0;
    const float* __restrict__ Vb = Vin + (size_t)j0 * RANK + c;

    float acc[6] = {0.f, 0.f, 0.f, 0.f, 0.f, 0.f};
#pragma unroll 10
    for (int t = 0; t < 150; ++t) {
        const float vc = Vb[(size_t)t * RANK];
#pragma unroll
        for (int r = 0; r < 6; ++r)
            acc[r] = fmaf(Wb[(size_t)r * NM + t], vc, acc[r]);
    }
#pragma unroll
    for (int r = 0; r < 6; ++r) part[wvid][r][c] = acc[r];
    __syncthreads();

    if (tid < 384) {
        const int r2 = tid >> 6, c2 = tid & 63;
        float s = 0.f;
#pragma unroll
        for (int k = 0; k < 8; ++k) s += part[k][r2][c2];
        const float lr = 1.0f / (sqrtf(2.0f * sumw2[0]) + 1e-8f);
        float y = Vin[(size_t)(i0 + r2) * RANK + c2] + lr * s;
        float n = wave_reduce_sum(y * y);
        Vout[(size_t)(i0 + r2) * RANK + c2] = y * (1.0f / sqrtf(n));
    }
}

// ---- out = clip(V V^T, 0, 1): 128x128 symmetric tiles, 8x8 frags ----
__global__ __launch_bounds__(256) void vvt_kernel(const float* __restrict__ V,
                                                  float* __restrict__ out) {
    const int bi = blockIdx.y, bj = blockIdx.x;
    if (bi > bj) return;
    __shared__ __align__(16) float Ti[64][132];   // [k][row]
    __shared__ __align__(16) float Tj[64][132];
    const int tid = threadIdx.x;
    for (int idx = tid; idx < 128 * 64; idx += 256) {
        int row = idx >> 6, k = idx & 63;
        int gi = bi * 128 + row, gj = bj * 128 + row;
        Ti[k][row] = (gi < NM) ? V[(size_t)gi * RANK + k] : 0.f;
        Tj[k][row] = (gj < NM) ? V[(size_t)gj * RANK + k] : 0.f;
    }
    __syncthreads();
    const int ty = tid >> 4, tx = tid & 15;
    float acc[8][8];
#pragma unroll
    for (int a = 0; a < 8; ++a)
#pragma unroll
        for (int b = 0; b < 8; ++b) acc[a][b] = 0.f;
    for (int k = 0; k < 64; ++k) {
        float4 a0 = *(const float4*)&Ti[k][ty * 8];
        float4 a1 = *(const float4*)&Ti[k][ty * 8 + 4];
        float4 b0 = *(const float4*)&Tj[k][tx * 8];
        float4 b1 = *(const float4*)&Tj[k][tx * 8 + 4];
        float av[8] = {a0.x, a0.y, a0.z, a0.w, a1.x, a1.y, a1.z, a1.w};
        float bv[8] = {b0.x, b0.y, b0.z, b0.w, b1.x, b1.y, b1.z, b1.w};
#pragma unroll
        for (int a = 0; a < 8; ++a)
#pragma unroll
            for (int b = 0; b < 8; ++b)
                acc[a][b] = fmaf(av[a], bv[b], acc[a][b]);
    }
#pragma unroll
    for (int a = 0; a < 8; ++a) {
        int i = bi * 128 + 8 * ty + a;
        if (i >= NM) break;
        int jb = bj * 128 + 8 * tx;
        if (jb + 7 < NM) {
            float4 s0 = {fminf(fmaxf(acc[a][0], 0.f), 1.f), fminf(fmaxf(acc[a][1], 0.f), 1.f),
                         fminf(fmaxf(acc[a][2], 0.f), 1.f), fminf(fmaxf(acc[a][3], 0.f), 1.f)};
            float4 s1 = {fminf(fmaxf(acc[a][4], 0.f), 1.f), fminf(fmaxf(acc[a][5], 0.f), 1.f),
                         fminf(fmaxf(acc[a][6], 0.f), 1.f), fminf(fmaxf(acc[a][7], 0.f), 1.f)};
            *(float4*)&out[(size_t)i * NM + jb] = s0;
            *(float4*)&out[(size_t)i * NM + jb + 4] = s1;
        } else {
#pragma unroll
            for (int b = 0; b < 8; ++b) {
                int j = jb + b;
                if (j < NM) out[(size_t)i * NM + j] = fminf(fmaxf(acc[a][b], 0.f), 1.f);
            }
        }
    }
    if (bi != bj) {
#pragma unroll
        for (int b = 0; b < 8; ++b) {
            int j = bj * 128 + 8 * tx + b;
            if (j >= NM) break;
            int ib = bi * 128 + 8 * ty;
            if (ib + 7 < NM) {
                float4 s0 = {fminf(fmaxf(acc[0][b], 0.f), 1.f), fminf(fmaxf(acc[1][b], 0.f), 1.f),
                             fminf(fmaxf(acc[2][b], 0.f), 1.f), fminf(fmaxf(acc[3][b], 0.f), 1.f)};
                float4 s1 = {fminf(fmaxf(acc[4][b], 0.f), 1.f), fminf(fmaxf(acc[5][b], 0.f), 1.f),
                             fminf(fmaxf(acc[6][b], 0.f), 1.f), fminf(fmaxf(acc[7][b], 0.f), 1.f)};
                *(float4*)&out[(size_t)j * NM + ib] = s0;
                *(float4*)&out[(size_t)j * NM + ib + 4] = s1;
            } else {
#pragma unroll
                for (int a = 0; a < 8; ++a) {
                    int i = ib + a;
                    if (i < NM) out[(size_t)j * NM + i] = fminf(fmaxf(acc[a][b], 0.f), 1.f);
                }
            }
        }
    }
}

extern "C" void kernel_launch(void* const* d_in, const int* in_sizes, int n_in,
                              void* d_out, int out_size, void* d_ws, size_t ws_size,
                              hipStream_t stream) {
    const float* x     = (const float*)d_in[0];
    const float* W1    = (const float*)d_in[1];
    const float* gamma = (const float*)d_in[3];
    const float* beta  = (const float*)d_in[4];
    const float* W2    = (const float*)d_in[5];
    const float* b2    = (const float*)d_in[6];
    const float* V0    = (const float*)d_in[7];
    float* out = (float*)d_out;

    float* ws    = (float*)d_ws;
    float* S     = ws + OFF_S;
    float* sumw2 = ws + OFF_SUMW2;
    float* cvec  = ws + OFF_CVEC;
    float* W1s   = ws + OFF_W1S;
    float* wvec  = ws + OFF_WVEC;
    float* Wmat  = ws + OFF_WMAT;
    float* Va    = ws + OFF_VA;
    float* Vb    = ws + OFF_VB;

    zero_kernel<<<7, 256, 0, stream>>>(ws, OFF_W1S);   // S + sumw2
    stats_kernel<<<STATS_BLOCKS, 256, 0, stream>>>(x, S);
    bn_prep<<<HID, 64, 0, stream>>>(S, W1, gamma, beta, W1s, cvec);
    mlp_kernel<<<(PP + 255) / 256, 256, 0, stream>>>(x, W1s, cvec, W2, b2, wvec, sumw2);
    buildW<<<dim3(75, 75), 256, 0, stream>>>(wvec, Wmat);
    v0norm<<<NM / 4, 256, 0, stream>>>(V0, Va);
    for (int it = 0; it < SDP_ITERS; ++it) {
        const float* vin = (it & 1) ? Vb : Va;
        float* vout      = (it & 1) ? Va : Vb;
        sdp_step<<<NM / 6, 512, 0, stream>>>(vin, vout, Wmat, sumw2);
    }
    // iter 99 (odd) writes Va
    vvt_kernel<<<dim3(10, 10), 256, 0, stream>>>(Va, out);
}